// Round 3
// baseline (555.701 us; speedup 1.0000x reference)
//
#include <hip/hip_runtime.h>

// RANGE2BEV: scatter range-view features (B,C,RH,RW) into BEV grid (B,C,D,W,H)
// with last-write-wins duplicate resolution (np fancy-assignment semantics).
//
//   pass 1: hipMemsetAsync winner = 0xFF (-1)
//   pass 2: per point, atomicMax(winner, i)  (largest point index wins)
//   pass 3: block = (b, 1024-cell chunk): winners -> registers once,
//           loop c=0..63: clamped unconditional gather + nontemporal float4 store.

namespace {

typedef float v4f __attribute__((ext_vector_type(4)));   // native vec for nontemporal store

constexpr int Wg    = 400;          // (40-(-40))/0.2
constexpr int Hg    = 352;          // (70.4-0)/0.2
constexpr int Dg    = 5;            // (1-(-3))/0.8
constexpr int NCELL = Dg * Wg * Hg; // 704000
constexpr int NPTS  = 64 * 2048;    // 131072 points per batch
constexpr int CC    = 64;
constexpr int BB    = 2;
constexpr int CPB   = 1024;         // cells per block (256 thr * 4)
constexpr int NCHUNK = (NCELL + CPB - 1) / CPB;  // 688 (last chunk = 512 cells)

__global__ void scatter_winner_k(const float* __restrict__ xyz,
                                 int* __restrict__ winner) {
    int idx = blockIdx.x * blockDim.x + threadIdx.x;
    if (idx >= BB * NPTS) return;
    int b = idx >> 17;              // / NPTS (131072)
    int i = idx & (NPTS - 1);
    const float* base = xyz + (size_t)b * 3 * NPTS;
    float xp = base[i];
    float yp = base[NPTS + i];
    float zp = base[2 * NPTS + i];
    if (!(zp >= -3.0f && zp < 1.0f)) return;          // valid z: [-3, 1)
    int zbin  = (int)floorf((zp + 3.0f) / 0.8f);      // [0,4], same f32 math as ref
    int x_img = (int)(-yp / 0.2f) + 200;              // trunc-toward-zero, f32 div
    int y_img = (int)(-xp / 0.2f) + 352;
    x_img = min(max(x_img, 0), Wg - 1);
    y_img = min(max(y_img, 0), Hg - 1);
    int xf = (Wg - 1) - x_img;
    int yf = (Hg - 1) - y_img;
    int cell = (zbin * Wg + xf) * Hg + yf;
    atomicMax(winner + b * NCELL + cell, i);          // last (largest i) wins
}

__global__ __launch_bounds__(256) void write_out_k(
        const float* __restrict__ feat,
        const int*   __restrict__ winner,
        float*       __restrict__ out) {
    int blk   = blockIdx.x;
    int b     = blk / NCHUNK;
    int chunk = blk - b * NCHUNK;
    int cell0 = chunk * CPB + (int)threadIdx.x * 4;
    if (cell0 >= NCELL) return;                       // tail of last chunk only

    const int4 w4 = *reinterpret_cast<const int4*>(winner + b * NCELL + cell0);
    const bool v0 = w4.x >= 0, v1 = w4.y >= 0, v2 = w4.z >= 0, v3 = w4.w >= 0;
    const int  i0 = max(w4.x, 0), i1 = max(w4.y, 0);
    const int  i2 = max(w4.z, 0), i3 = max(w4.w, 0);

    const float* fb = feat + (size_t)b * CC * NPTS;
    float*       ob = out  + (size_t)b * CC * NCELL + cell0;

#pragma unroll 2
    for (int c = 0; c < CC; ++c) {
        const float* frow = fb + (size_t)c * NPTS;
        // unconditional (clamped) gathers: no exec-mask divergence; i*=0 is safe
        float g0 = frow[i0], g1 = frow[i1], g2 = frow[i2], g3 = frow[i3];
        v4f v;
        v.x = v0 ? g0 : 0.0f;
        v.y = v1 ? g1 : 0.0f;
        v.z = v2 ? g2 : 0.0f;
        v.w = v3 ? g3 : 0.0f;
        __builtin_nontemporal_store(v, reinterpret_cast<v4f*>(ob + (size_t)c * NCELL));
    }
}

} // namespace

extern "C" void kernel_launch(void* const* d_in, const int* in_sizes, int n_in,
                              void* d_out, int out_size, void* d_ws, size_t ws_size,
                              hipStream_t stream) {
    const float* range_res = (const float*)d_in[0];   // (B,C,RH,RW) f32
    const float* xyz       = (const float*)d_in[1];   // (B,3,RH,RW) f32
    float* out             = (float*)d_out;           // (B,C,D,W,H) f32
    int* winner            = (int*)d_ws;              // BB*NCELL ints = 5.6 MB

    // winner = -1 via byte pattern 0xFF (graph-capturable memset node)
    (void)hipMemsetAsync(winner, 0xFF, (size_t)BB * NCELL * sizeof(int), stream);

    {
        int total = BB * NPTS;
        scatter_winner_k<<<(total + 255) / 256, 256, 0, stream>>>(xyz, winner);
    }
    {
        int blocks = BB * NCHUNK;                     // 1376
        write_out_k<<<blocks, 256, 0, stream>>>(range_res, winner, out);
    }
}

// Round 5
// 488.933 us; speedup vs baseline: 1.1366x; 1.1366x over previous
//
#include <hip/hip_runtime.h>

// RANGE2BEV: scatter range-view features (B,C,RH,RW) into BEV grid (B,C,D,W,H)
// with last-write-wins duplicate resolution (np fancy-assignment semantics).
//
//   pass 1: hipMemsetAsync winner = 0xFF (-1)
//   pass 2: per point, atomicMax(winner, i)  (largest point index wins)
//   pass 3: block = (b, c, 1/8 cell chunk): each block gathers from ONE
//           512 KB feat row (L2-resident, shared by its 8 sibling blocks via
//           XCD-colocating blockIdx mapping), writes coalesced nt float4.

namespace {

typedef float v4f __attribute__((ext_vector_type(4)));

constexpr int Wg    = 400;          // (40-(-40))/0.2
constexpr int Hg    = 352;          // (70.4-0)/0.2
constexpr int Dg    = 5;            // (1-(-3))/0.8
constexpr int NCELL = Dg * Wg * Hg; // 704000
constexpr int NPTS  = 64 * 2048;    // 131072 points per batch
constexpr int CC    = 64;
constexpr int BB    = 2;
constexpr int Q     = 8;                          // cell chunks per channel
constexpr int CPC   = NCELL / Q;                  // 88000 cells per chunk
constexpr int VPC   = CPC / 4;                    // 22000 int4/float4 vecs per chunk

__global__ void scatter_winner_k(const float* __restrict__ xyz,
                                 int* __restrict__ winner) {
    int idx = blockIdx.x * blockDim.x + threadIdx.x;
    if (idx >= BB * NPTS) return;
    int b = idx >> 17;              // / NPTS (131072)
    int i = idx & (NPTS - 1);
    const float* base = xyz + (size_t)b * 3 * NPTS;
    float xp = base[i];
    float yp = base[NPTS + i];
    float zp = base[2 * NPTS + i];
    if (!(zp >= -3.0f && zp < 1.0f)) return;          // valid z: [-3, 1)
    int zbin  = (int)floorf((zp + 3.0f) / 0.8f);      // [0,4], same f32 math as ref
    int x_img = (int)(-yp / 0.2f) + 200;              // trunc-toward-zero, f32 div
    int y_img = (int)(-xp / 0.2f) + 352;
    x_img = min(max(x_img, 0), Wg - 1);
    y_img = min(max(y_img, 0), Hg - 1);
    int xf = (Wg - 1) - x_img;
    int yf = (Hg - 1) - y_img;
    int cell = (zbin * Wg + xf) * Hg + yf;
    atomicMax(winner + b * NCELL + cell, i);          // last (largest i) wins
}

// blockIdx = (bc>>3)*64 + q*8 + (bc&7)   (bijective over 1024)
//   => blk % 8 == bc % 8: all 8 q-siblings of a (b,c) land on the SAME XCD
//      and are 8 apart in dispatch order (temporally adjacent) -> the 512 KB
//      feat row is fetched from HBM ~once and served from that XCD's L2.
__global__ __launch_bounds__(256) void write_out_k(
        const float* __restrict__ feat,
        const int*   __restrict__ winner,
        float*       __restrict__ out) {
    int blk  = blockIdx.x;
    int x    = blk & 7;
    int q    = (blk >> 3) & 7;
    int bchi = blk >> 6;
    int bc   = bchi * 8 + x;          // b*64 + c
    int b    = bc >> 6;

    const int*   wbase = winner + b * NCELL + q * CPC;
    const float* frow  = feat + (size_t)bc * NPTS;          // one 512 KB row
    float*       obase = out + (size_t)bc * NCELL + q * CPC;

#pragma unroll 2
    for (int i = threadIdx.x; i < VPC; i += 256) {
        const int4 w4 = reinterpret_cast<const int4*>(wbase)[i];
        // unconditional clamped gathers: no exec-mask divergence; idx 0 is safe
        float g0 = frow[max(w4.x, 0)];
        float g1 = frow[max(w4.y, 0)];
        float g2 = frow[max(w4.z, 0)];
        float g3 = frow[max(w4.w, 0)];
        v4f v;
        v.x = (w4.x >= 0) ? g0 : 0.0f;
        v.y = (w4.y >= 0) ? g1 : 0.0f;
        v.z = (w4.z >= 0) ? g2 : 0.0f;
        v.w = (w4.w >= 0) ? g3 : 0.0f;
        __builtin_nontemporal_store(v, reinterpret_cast<v4f*>(obase) + i);
    }
}

} // namespace

extern "C" void kernel_launch(void* const* d_in, const int* in_sizes, int n_in,
                              void* d_out, int out_size, void* d_ws, size_t ws_size,
                              hipStream_t stream) {
    const float* range_res = (const float*)d_in[0];   // (B,C,RH,RW) f32
    const float* xyz       = (const float*)d_in[1];   // (B,3,RH,RW) f32
    float* out             = (float*)d_out;           // (B,C,D,W,H) f32
    int* winner            = (int*)d_ws;              // BB*NCELL ints = 5.6 MB

    // winner = -1 via byte pattern 0xFF (graph-capturable memset node)
    (void)hipMemsetAsync(winner, 0xFF, (size_t)BB * NCELL * sizeof(int), stream);

    {
        int total = BB * NPTS;
        scatter_winner_k<<<(total + 255) / 256, 256, 0, stream>>>(xyz, winner);
    }
    {
        int blocks = BB * CC * Q;                     // 1024
        write_out_k<<<blocks, 256, 0, stream>>>(range_res, winner, out);
    }
}

// Round 6
// 445.883 us; speedup vs baseline: 1.2463x; 1.0966x over previous
//
#include <hip/hip_runtime.h>

// RANGE2BEV: scatter range-view features (B,C,RH,RW) into BEV grid (B,C,D,W,H)
// with last-write-wins duplicate resolution (np fancy-assignment semantics).
//
//   pass 1: hipMemsetAsync winner = 0xFF (-1)
//   pass 2: per point, atomicMax(winner, i)   (largest point index wins)
//   pass 3: transpose feat (b,c,n) -> featT (b,n,c)   [coalesced both ways]
//   pass 4: per 64-cell block: winners -> LDS, gather featT rows (256 B
//           contiguous per cell, 4 line-reqs instead of 64 divergent),
//           LDS transpose, coalesced nontemporal out writes.

namespace {

constexpr int Wg    = 400;          // (40-(-40))/0.2
constexpr int Hg    = 352;          // (70.4-0)/0.2
constexpr int Dg    = 5;            // (1-(-3))/0.8
constexpr int NCELL = Dg * Wg * Hg; // 704000
constexpr int NPTS  = 64 * 2048;    // 131072 points per batch
constexpr int CC    = 64;
constexpr int BB    = 2;
constexpr int GRP   = 64;           // cells per block in bev pass
constexpr int NGRP  = NCELL / GRP;  // 11000

__global__ void scatter_winner_k(const float* __restrict__ xyz,
                                 int* __restrict__ winner) {
    int idx = blockIdx.x * blockDim.x + threadIdx.x;
    if (idx >= BB * NPTS) return;
    int b = idx >> 17;              // / NPTS (131072)
    int i = idx & (NPTS - 1);
    const float* base = xyz + (size_t)b * 3 * NPTS;
    float xp = base[i];
    float yp = base[NPTS + i];
    float zp = base[2 * NPTS + i];
    if (!(zp >= -3.0f && zp < 1.0f)) return;          // valid z: [-3, 1)
    int zbin  = (int)floorf((zp + 3.0f) / 0.8f);      // [0,4], same f32 math as ref
    int x_img = (int)(-yp / 0.2f) + 200;              // trunc-toward-zero, f32 div
    int y_img = (int)(-xp / 0.2f) + 352;
    x_img = min(max(x_img, 0), Wg - 1);
    y_img = min(max(y_img, 0), Hg - 1);
    int xf = (Wg - 1) - x_img;
    int yf = (Hg - 1) - y_img;
    int cell = (zbin * Wg + xf) * Hg + yf;
    atomicMax(winner + b * NCELL + cell, i);          // last (largest i) wins
}

// feat (b, c=64, n) -> featT (b, n, c=64); 64x64 LDS tiles, 2048 tiles per b.
__global__ __launch_bounds__(256) void transpose_k(const float* __restrict__ feat,
                                                   float* __restrict__ featT) {
    __shared__ float tile[64][65];
    int blk = blockIdx.x;
    int b   = blk >> 11;                  // 2048 tiles per batch
    int n0  = (blk & 2047) * 64;
    const float* fb = feat  + (size_t)b * CC * NPTS;
    float*       tb = featT + (size_t)b * NPTS * CC;
    int t = threadIdx.x;
#pragma unroll
    for (int k = 0; k < 16; ++k) {
        int j = k * 256 + t;
        int c = j >> 6, nn = j & 63;      // wave: c uniform, nn = lane -> coalesced
        tile[c][nn] = fb[(size_t)c * NPTS + n0 + nn];
    }
    __syncthreads();
#pragma unroll
    for (int k = 0; k < 16; ++k) {
        int j = k * 256 + t;
        int nn = j >> 6, c = j & 63;      // wave: nn uniform, c = lane -> coalesced
        tb[(size_t)(n0 + nn) * CC + c] = tile[c][nn];
    }
}

// One block = 64 consecutive cells of one batch. Gather featT rows coalesced,
// transpose through LDS, write out coalesced (c-major layout).
__global__ __launch_bounds__(256) void bev_write_k(const float* __restrict__ featT,
                                                   const int*   __restrict__ winner,
                                                   float*       __restrict__ out) {
    __shared__ float tile[GRP][65];
    __shared__ int   wins[GRP];
    int blk   = blockIdx.x;
    int b     = blk / NGRP;
    int cell0 = (blk - b * NGRP) * GRP;
    int t     = threadIdx.x;

    if (t < GRP) wins[t] = winner[b * NCELL + cell0 + t];   // 256 B coalesced
    __syncthreads();

    const float* ftb = featT + (size_t)b * NPTS * CC;
    // stage 1: per wave-iteration, one cell's 64-channel row (256 B contiguous)
#pragma unroll
    for (int k = 0; k < 16; ++k) {
        int j = k * 256 + t;
        int g = j >> 6;                   // wave-uniform cell within group
        int c = j & 63;                   // lane = channel
        int pt = wins[g];
        float v = 0.0f;
        if (pt >= 0) v = ftb[(size_t)pt * CC + c];   // wave-uniform branch
        tile[g][c] = v;
    }
    __syncthreads();
    // stage 2: coalesced writes, channel-major
    float* ob = out + (size_t)b * CC * NCELL + cell0;
#pragma unroll
    for (int k = 0; k < 16; ++k) {
        int j = k * 256 + t;
        int c = j >> 6;                   // wave-uniform channel
        int g = j & 63;                   // lane = cell -> coalesced 256 B
        __builtin_nontemporal_store(tile[g][c], ob + (size_t)c * NCELL + g);
    }
}

} // namespace

extern "C" void kernel_launch(void* const* d_in, const int* in_sizes, int n_in,
                              void* d_out, int out_size, void* d_ws, size_t ws_size,
                              hipStream_t stream) {
    const float* range_res = (const float*)d_in[0];   // (B,C,RH,RW) f32
    const float* xyz       = (const float*)d_in[1];   // (B,3,RH,RW) f32
    float* out             = (float*)d_out;           // (B,C,D,W,H) f32
    int*   winner          = (int*)d_ws;              // BB*NCELL ints = 5.6 MB
    float* featT           = (float*)((char*)d_ws + (8u << 20));  // 64 MB at +8 MB

    // winner = -1 via byte pattern 0xFF (graph-capturable memset node)
    (void)hipMemsetAsync(winner, 0xFF, (size_t)BB * NCELL * sizeof(int), stream);

    {
        int total = BB * NPTS;
        scatter_winner_k<<<(total + 255) / 256, 256, 0, stream>>>(xyz, winner);
    }
    {
        int blocks = BB * (NPTS / 64);                // 4096
        transpose_k<<<blocks, 256, 0, stream>>>(range_res, featT);
    }
    {
        int blocks = BB * NGRP;                       // 22000
        bev_write_k<<<blocks, 256, 0, stream>>>(featT, winner, out);
    }
}